// Round 18
// baseline (761.338 us; speedup 1.0000x reference)
//
#include <hip/hip_runtime.h>
#include <hip/hip_bf16.h>

typedef __attribute__((ext_vector_type(8))) short short8v;
typedef __attribute__((ext_vector_type(4))) float f32x4;
typedef __attribute__((ext_vector_type(16))) float f32x16;
typedef __hip_bfloat16 bf16;

#define BDIM 512
#define NHEADS 8
#define DK 64
#define NBATCH 256
#define NN3 256
#define NN4 64
#define NMLP 2048

#define GLOAD_LDS16(g, l)                                                  \
  __builtin_amdgcn_global_load_lds(                                        \
      (const __attribute__((address_space(1))) void*)(g),                  \
      (__attribute__((address_space(3))) void*)(l), 16, 0, 0)

__device__ __forceinline__ float bf2f(short s) {
  union { short u[2]; float f; } cv;
  cv.u[0] = 0; cv.u[1] = s;
  return cv.f;
}
__device__ __forceinline__ short f2bf(float x) {
  bf16 h = __float2bfloat16(x);
  return *reinterpret_cast<short*>(&h);
}

// ------- coalesced transposing convert: Wt[n][k] = bf16(W[k][n]) ----------
__global__ __launch_bounds__(256) void convt_kernel(
    const float* __restrict__ W, bf16* __restrict__ Wt, int K, int N) {
  __shared__ float tile[32][33];
  int bx = blockIdx.x * 32, by = blockIdx.y * 32;
  int tx = threadIdx.x, ty = threadIdx.y;
#pragma unroll
  for (int j = 0; j < 32; j += 8)
    tile[ty + j][tx] = W[(size_t)(by + ty + j) * N + bx + tx];
  __syncthreads();
#pragma unroll
  for (int j = 0; j < 32; j += 8)
    Wt[(size_t)(bx + ty + j) * K + by + tx] = __float2bfloat16(tile[tx][ty + j]);
}

// ------- wave-per-row LayerNorm (f32 in), +pos, optional extra outs -------
__global__ __launch_bounds__(256) void ln_kernel(
    const float* __restrict__ x, const float* __restrict__ g,
    const float* __restrict__ beta, const float* __restrict__ pos, int nmod,
    bf16* __restrict__ out1, bf16* __restrict__ out2, bf16* __restrict__ raw) {
  int w = threadIdx.x >> 6, lane = threadIdx.x & 63;
  int row = blockIdx.x * 4 + w;
  int c0 = lane * 8;
  const float* xr = x + (size_t)row * BDIM + c0;
  float4 v0 = *(const float4*)xr;
  float4 v1 = *(const float4*)(xr + 4);
  float f[8] = {v0.x, v0.y, v0.z, v0.w, v1.x, v1.y, v1.z, v1.w};
  float s = 0.f, sq = 0.f;
#pragma unroll
  for (int i = 0; i < 8; i++) {
    s += f[i];
    sq += f[i] * f[i];
  }
#pragma unroll
  for (int o = 1; o <= 32; o <<= 1) {
    s += __shfl_xor(s, o);
    sq += __shfl_xor(sq, o);
  }
  float mean = s * (1.f / BDIM);
  float var = sq * (1.f / BDIM) - mean * mean;
  float rstd = rsqrtf(var + 1e-5f);
  float4 g0 = *(const float4*)(g + c0);
  float4 g1 = *(const float4*)(g + c0 + 4);
  float4 b0 = *(const float4*)(beta + c0);
  float4 b1 = *(const float4*)(beta + c0 + 4);
  float gg[8] = {g0.x, g0.y, g0.z, g0.w, g1.x, g1.y, g1.z, g1.w};
  float bb[8] = {b0.x, b0.y, b0.z, b0.w, b1.x, b1.y, b1.z, b1.w};
  float pv[8] = {};
  if (pos) {
    int n = row % nmod;
    const float* pr = pos + (size_t)n * BDIM + c0;
    float4 p0 = *(const float4*)pr;
    float4 p1 = *(const float4*)(pr + 4);
    pv[0] = p0.x; pv[1] = p0.y; pv[2] = p0.z; pv[3] = p0.w;
    pv[4] = p1.x; pv[5] = p1.y; pv[6] = p1.z; pv[7] = p1.w;
  }
  short8v o1, o2, rw;
#pragma unroll
  for (int i = 0; i < 8; i++) {
    float nv = (f[i] - mean) * rstd * gg[i] + bb[i];
    o1[i] = f2bf(nv + pv[i]);
    o2[i] = f2bf(nv);
    rw[i] = f2bf(f[i]);
  }
  size_t ob = (size_t)row * BDIM + c0;
  *(short8v*)(out1 + ob) = o1;
  if (out2) *(short8v*)(out2 + ob) = o2;
  if (raw) *(short8v*)(raw + ob) = rw;
}

// ---------- wave-per-row LayerNorm (bf16 in, bf16 out) --------------------
__global__ __launch_bounds__(256) void lnb_kernel(
    const bf16* __restrict__ x, const float* __restrict__ g,
    const float* __restrict__ beta, bf16* __restrict__ out) {
  int w = threadIdx.x >> 6, lane = threadIdx.x & 63;
  int row = blockIdx.x * 4 + w;
  int c0 = lane * 8;
  short8v v = *(const short8v*)(x + (size_t)row * BDIM + c0);
  float f[8];
  float s = 0.f, sq = 0.f;
#pragma unroll
  for (int i = 0; i < 8; i++) {
    f[i] = bf2f(v[i]);
    s += f[i];
    sq += f[i] * f[i];
  }
#pragma unroll
  for (int o = 1; o <= 32; o <<= 1) {
    s += __shfl_xor(s, o);
    sq += __shfl_xor(sq, o);
  }
  float mean = s * (1.f / BDIM);
  float var = sq * (1.f / BDIM) - mean * mean;
  float rstd = rsqrtf(var + 1e-5f);
  float4 g0 = *(const float4*)(g + c0);
  float4 g1 = *(const float4*)(g + c0 + 4);
  float4 b0 = *(const float4*)(beta + c0);
  float4 b1 = *(const float4*)(beta + c0 + 4);
  float gg[8] = {g0.x, g0.y, g0.z, g0.w, g1.x, g1.y, g1.z, g1.w};
  float bb[8] = {b0.x, b0.y, b0.z, b0.w, b1.x, b1.y, b1.z, b1.w};
  short8v o1;
#pragma unroll
  for (int i = 0; i < 8; i++) o1[i] = f2bf((f[i] - mean) * rstd * gg[i] + bb[i]);
  *(short8v*)(out + (size_t)row * BDIM + c0) = o1;
}

// ---------------- pipelined MFMA GEMM: out[M,N] = X[M,K] @ Wt[N,K]^T ------
// 128x128 tile, 8 waves (2x4) of 64x32, BK=64, 2 LDS buffers (64KB ->
// 2 blocks/CU), counted-vmcnt depth-2 prefetch, 2 raw barriers per K-step.
// Inner tile: v_mfma_f32_32x32x16_bf16 (2 per wave per k-chunk of 16; same
// 12 ds_read_b128 per K-step as the 16x16 variant, half the MFMA count).
// EPI 0: bf16 out = acc + bias
// EPI 1: bf16 out = gelu_tanh(acc + bias)
// EPI 3: bf16 out = srcbf16[o] + acc + bias
// EPI 4: f32  out = srcbf16[o] + acc + bias
template <int EPI, int K, int LDX, int LDW, int N, int GX>
__global__ __launch_bounds__(512) void gemm_kernel(
    const bf16* __restrict__ X, const bf16* __restrict__ Wt,
    const float* __restrict__ bias, const void* __restrict__ src, void* outp) {
  extern __shared__ bf16 lds[];  // 2 x 16384 elems = 64KB

  int nwg = gridDim.x;
  int cpx = nwg >> 3;
  int bid = blockIdx.x;
  int nb = (bid & 7) * cpx + (bid >> 3);
  int bx = nb % GX, by = nb / GX;
  int row0 = by * 128, col0 = bx * 128;

  int t = threadIdx.x, w = t >> 6, lane = t & 63;
  int wr = w >> 2, wc = w & 3;
  int r32 = lane & 31, kg2 = lane >> 5;  // 32x32 fragment coords
  int srow = lane >> 3;
  int scol = ((lane & 7) ^ srow) * 8;

  const bf16* gA0 = X + (size_t)(row0 + w * 16 + srow) * LDX + scol;
  const bf16* gB0 = Wt + (size_t)(col0 + w * 16 + srow) * LDW + scol;

  f32x16 acc[2] = {};

  auto stage = [&](int kt, int buf) {
    bf16* base = lds + buf * 16384;
    int ke = kt << 6;
#pragma unroll
    for (int j = 0; j < 2; j++) {
      GLOAD_LDS16(gA0 + ke + (size_t)j * 8 * LDX, base + (w * 16 + j * 8) * 64);
      GLOAD_LDS16(gB0 + ke + (size_t)j * 8 * LDW,
                  base + 8192 + (w * 16 + j * 8) * 64);
    }
  };

  auto compute = [&](int buf) {
    const char* base = (const char*)(lds + buf * 16384);
#pragma unroll
    for (int kc = 0; kc < 4; kc++) {     // K chunks of 16
      int slot = kc * 2 + kg2;           // 16B slot 0..7 within 128B row
      short8v a[2], b;
#pragma unroll
      for (int mt = 0; mt < 2; mt++) {
        int rl = wr * 64 + mt * 32 + r32;
        a[mt] = *(const short8v*)(base + rl * 128 + ((slot ^ (rl & 7)) << 4));
      }
      int cl = wc * 32 + r32;
      b = *(const short8v*)(base + 16384 + cl * 128 + ((slot ^ (cl & 7)) << 4));
#pragma unroll
      for (int mt = 0; mt < 2; mt++)
        acc[mt] =
            __builtin_amdgcn_mfma_f32_32x32x16_bf16(a[mt], b, acc[mt], 0, 0, 0);
    }
  };

  constexpr int NT = K >> 6;
  stage(0, 0);
  stage(1, 1);
#pragma unroll
  for (int tt = 0; tt < NT; tt++) {
    if (tt < NT - 1)
      asm volatile("s_waitcnt vmcnt(4)" ::: "memory");
    else
      asm volatile("s_waitcnt vmcnt(0)" ::: "memory");
    __builtin_amdgcn_s_barrier();
    asm volatile("" ::: "memory");
    compute(tt & 1);
    asm volatile("" ::: "memory");
    __builtin_amdgcn_s_barrier();
    asm volatile("" ::: "memory");
    if (tt + 2 < NT) stage(tt + 2, tt & 1);
  }

  // epilogue: C/D layout (32x32): col=lane&31, row=(reg&3)+8*(reg>>2)+4*kg2
  int col = col0 + wc * 32 + r32;
  float bv = bias ? bias[col] : 0.f;
#pragma unroll
  for (int mt = 0; mt < 2; mt++)
#pragma unroll
    for (int reg = 0; reg < 16; reg++) {
      int row = row0 + wr * 64 + mt * 32 + (reg & 3) + 8 * (reg >> 2) + 4 * kg2;
      size_t o = (size_t)row * N + col;
      float val = acc[mt][reg] + bv;
      if (EPI == 0) {
        ((bf16*)outp)[o] = __float2bfloat16(val);
      } else if (EPI == 1) {
        // gelu_tanh(x) = x * sigmoid(1.5957691*(x + 0.044715 x^3))
        float z = 1.5957691f * val * (1.f + 0.044715f * val * val);
        float gl = val / (1.f + __expf(-z));
        ((bf16*)outp)[o] = __float2bfloat16(gl);
      } else if (EPI == 3) {
        ((bf16*)outp)[o] = __float2bfloat16(bf2f(((const short*)src)[o]) + val);
      } else {
        ((float*)outp)[o] = bf2f(((const short*)src)[o]) + val;
      }
    }
}

// ---- ctx: fused k-softmax (over positions) + ctxT[bh][vc][kc] einsum -----
__global__ __launch_bounds__(256) void ctx_kernel(
    const bf16* __restrict__ kproj, const bf16* __restrict__ vbuf,
    bf16* __restrict__ ctxT) {
  int bh = blockIdx.x;
  int b = bh >> 3, h = bh & 7;
  __shared__ bf16 lk[NN4][DK], lv[NN4][DK];
  int t = threadIdx.x;
#pragma unroll
  for (int i = 0; i < 16; i++) {
    int idx = i * 256 + t;
    int n = idx >> 6, c = idx & 63;
    size_t gaddr = (size_t)b * NN4 * BDIM + (size_t)n * BDIM + h * DK + c;
    lk[n][c] = kproj[gaddr];
    lv[n][c] = vbuf[gaddr];
  }
  __syncthreads();
  if (t < 64) {
    int c = t;
    float e[NN4];
    float m = -1e30f;
#pragma unroll
    for (int n = 0; n < NN4; n++) {
      e[n] = bf2f(*(short*)&lk[n][c]);
      m = fmaxf(m, e[n]);
    }
    float s = 0.f;
#pragma unroll
    for (int n = 0; n < NN4; n++) {
      e[n] = __expf(e[n] - m);
      s += e[n];
    }
    float inv = 1.f / s;
#pragma unroll
    for (int n = 0; n < NN4; n++) lk[n][c] = __float2bfloat16(e[n] * inv);
  }
  __syncthreads();
  int vc = t >> 2;
  int kc0 = (t & 3) * 16;
  float acc[16] = {};
  for (int n = 0; n < NN4; n++) {
    float vv = __bfloat162float(lv[n][vc]);
#pragma unroll
    for (int i = 0; i < 16; i++)
      acc[i] += vv * __bfloat162float(lk[n][kc0 + i]);
  }
  size_t o = (size_t)bh * 4096 + (size_t)vc * 64 + kc0;
#pragma unroll
  for (int i = 0; i < 16; i++) ctxT[o + i] = __float2bfloat16(acc[i]);
}

// ---- att: fused q-softmax (in-register, over 64 head channels) + GEMM ----
__global__ __launch_bounds__(256) void att_kernel(
    const bf16* __restrict__ qproj, const bf16* __restrict__ ctxT,
    bf16* __restrict__ att) {
  int bh = blockIdx.x;
  int b = bh >> 3, h = bh & 7;
  int t = threadIdx.x, w = t >> 6, lane = t & 63;
  int r16 = lane & 15, kg = lane >> 4;
  f32x4 acc[4][4] = {};
  const bf16* qb = qproj + (size_t)b * NN3 * BDIM + h * DK;
  const bf16* cb = ctxT + (size_t)bh * 4096;
  short8v bb[2][4];
#pragma unroll
  for (int kt = 0; kt < 2; kt++)
#pragma unroll
    for (int ni = 0; ni < 4; ni++)
      bb[kt][ni] = *(const short8v*)(cb + (ni * 16 + r16) * 64 + kt * 32 + kg * 8);
#pragma unroll
  for (int mi = 0; mi < 4; mi++) {
    int rrow = w * 64 + mi * 16 + r16;
    short8v a0 = *(const short8v*)(qb + (size_t)rrow * BDIM + kg * 8);
    short8v a1 = *(const short8v*)(qb + (size_t)rrow * BDIM + 32 + kg * 8);
    float f[16];
#pragma unroll
    for (int i = 0; i < 8; i++) {
      f[i] = bf2f(a0[i]);
      f[8 + i] = bf2f(a1[i]);
    }
    float m = f[0];
#pragma unroll
    for (int i = 1; i < 16; i++) m = fmaxf(m, f[i]);
    m = fmaxf(m, __shfl_xor(m, 16));
    m = fmaxf(m, __shfl_xor(m, 32));
    float s = 0.f;
#pragma unroll
    for (int i = 0; i < 16; i++) {
      f[i] = __expf(f[i] - m);
      s += f[i];
    }
    s += __shfl_xor(s, 16);
    s += __shfl_xor(s, 32);
    float inv = 1.f / s;
    short8v A0, A1;
#pragma unroll
    for (int i = 0; i < 8; i++) {
      A0[i] = f2bf(f[i] * inv);
      A1[i] = f2bf(f[8 + i] * inv);
    }
#pragma unroll
    for (int ni = 0; ni < 4; ni++) {
      acc[mi][ni] = __builtin_amdgcn_mfma_f32_16x16x32_bf16(A0, bb[0][ni], acc[mi][ni], 0, 0, 0);
      acc[mi][ni] = __builtin_amdgcn_mfma_f32_16x16x32_bf16(A1, bb[1][ni], acc[mi][ni], 0, 0, 0);
    }
  }
#pragma unroll
  for (int mi = 0; mi < 4; mi++)
#pragma unroll
    for (int ni = 0; ni < 4; ni++)
#pragma unroll
      for (int r = 0; r < 4; r++) {
        int row = w * 64 + mi * 16 + kg * 4 + r;
        int col = ni * 16 + r16;
        att[(size_t)(b * NN3 + row) * BDIM + h * DK + col] =
            __float2bfloat16(acc[mi][ni][r]);
      }
}

extern "C" void kernel_launch(void* const* d_in, const int* in_sizes, int n_in,
                              void* d_out, int out_size, void* d_ws, size_t ws_size,
                              hipStream_t stream) {
  const float* f3 = (const float*)d_in[0];
  const float* f4 = (const float*)d_in[1];
  const float* pos3 = (const float*)d_in[2];
  const float* pos4 = (const float*)d_in[3];
  const float* ln1_g = (const float*)d_in[4];
  const float* ln1_b = (const float*)d_in[5];
  const float* ln2_g = (const float*)d_in[6];
  const float* ln2_b = (const float*)d_in[7];
  const float* ln3_g = (const float*)d_in[8];
  const float* ln3_b = (const float*)d_in[9];
  const float* Wq = (const float*)d_in[10];
  const float* bq = (const float*)d_in[11];
  const float* Wk = (const float*)d_in[12];
  const float* bk = (const float*)d_in[13];
  const float* Wv = (const float*)d_in[14];
  const float* bv = (const float*)d_in[15];
  const float* Wr = (const float*)d_in[16];
  const float* br = (const float*)d_in[17];
  const float* W1 = (const float*)d_in[18];
  const float* b1 = (const float*)d_in[19];
  const float* W2 = (const float*)d_in[20];
  const float* b2 = (const float*)d_in[21];
  float* out = (float*)d_out;

  const int M3 = NBATCH * NN3;  // 65536
  const int M4 = NBATCH * NN4;  // 16384
  const int MC = M3 / 2;        // 32768 MLP row-chunk

  char* ws = (char*)d_ws;
  size_t off = 0;
  auto alloc = [&](size_t bytes) {
    size_t r = off;
    off = (off + bytes + 255) & ~(size_t)255;
    return r;
  };
  size_t oWqt = alloc((size_t)BDIM * BDIM * 2);
  size_t oWkt = alloc((size_t)BDIM * BDIM * 2);
  size_t oWvt = alloc((size_t)BDIM * BDIM * 2);
  size_t oWrt = alloc((size_t)BDIM * BDIM * 2);
  size_t oW1t = alloc((size_t)BDIM * NMLP * 2);
  size_t oW2t = alloc((size_t)BDIM * NMLP * 2);
  size_t oXQ = alloc((size_t)M3 * BDIM * 2);  // ln(f3)+pos3 -> att -> Yn
  size_t oXK = alloc((size_t)M4 * BDIM * 2);
  size_t oXV = alloc((size_t)M4 * BDIM * 2);
  size_t oQF = alloc((size_t)M3 * BDIM * 2);  // q proj -> F3O
  size_t oKF = alloc((size_t)M4 * BDIM * 2);
  size_t oVF = alloc((size_t)M4 * BDIM * 2);
  size_t oF3B = alloc((size_t)M3 * BDIM * 2);  // bf16 copy of f3
  size_t oCT = alloc((size_t)NBATCH * NHEADS * DK * DK * 2);
  size_t oH1 = alloc((size_t)MC * NMLP * 2);  // 128MB hidden row-chunk
  (void)ws_size;

  bf16* Wqt = (bf16*)(ws + oWqt);
  bf16* Wkt = (bf16*)(ws + oWkt);
  bf16* Wvt = (bf16*)(ws + oWvt);
  bf16* Wrt = (bf16*)(ws + oWrt);
  bf16* W1t = (bf16*)(ws + oW1t);
  bf16* W2t = (bf16*)(ws + oW2t);
  bf16* XQ = (bf16*)(ws + oXQ);
  bf16* XK = (bf16*)(ws + oXK);
  bf16* XV = (bf16*)(ws + oXV);
  bf16* QF = (bf16*)(ws + oQF);
  bf16* KF = (bf16*)(ws + oKF);
  bf16* VF = (bf16*)(ws + oVF);
  bf16* F3B = (bf16*)(ws + oF3B);
  bf16* CT = (bf16*)(ws + oCT);
  bf16* H1 = (bf16*)(ws + oH1);
  bf16* ATT = XQ;   // reuse (XQ dead after q projection)
  bf16* F3O = QF;   // reuse (QF dead after att)
  bf16* YN = XQ;    // reuse (ATT dead after outproj)

  // dynamic-LDS caps for the 4 GEMM instantiations
  hipFuncSetAttribute((const void*)gemm_kernel<0, 512, 512, 512, 512, 4>,
                      hipFuncAttributeMaxDynamicSharedMemorySize, 65536);
  hipFuncSetAttribute((const void*)gemm_kernel<1, 512, 512, 512, 2048, 16>,
                      hipFuncAttributeMaxDynamicSharedMemorySize, 65536);
  hipFuncSetAttribute((const void*)gemm_kernel<3, 512, 512, 512, 512, 4>,
                      hipFuncAttributeMaxDynamicSharedMemorySize, 65536);
  hipFuncSetAttribute((const void*)gemm_kernel<4, 2048, 2048, 2048, 512, 4>,
                      hipFuncAttributeMaxDynamicSharedMemorySize, 65536);

  // ---- weight conversion (coalesced LDS-tile transpose) ----
  convt_kernel<<<dim3(BDIM / 32, BDIM / 32), dim3(32, 8), 0, stream>>>(Wq, Wqt, BDIM, BDIM);
  convt_kernel<<<dim3(BDIM / 32, BDIM / 32), dim3(32, 8), 0, stream>>>(Wk, Wkt, BDIM, BDIM);
  convt_kernel<<<dim3(BDIM / 32, BDIM / 32), dim3(32, 8), 0, stream>>>(Wv, Wvt, BDIM, BDIM);
  convt_kernel<<<dim3(BDIM / 32, BDIM / 32), dim3(32, 8), 0, stream>>>(Wr, Wrt, BDIM, BDIM);
  convt_kernel<<<dim3(NMLP / 32, BDIM / 32), dim3(32, 8), 0, stream>>>(W1, W1t, BDIM, NMLP);
  convt_kernel<<<dim3(BDIM / 32, NMLP / 32), dim3(32, 8), 0, stream>>>(W2, W2t, NMLP, BDIM);

  // ---- layernorms (f3 pass also emits bf16 raw copy for residual) ----
  ln_kernel<<<M3 / 4, 256, 0, stream>>>(f3, ln1_g, ln1_b, pos3, NN3, XQ, nullptr, F3B);
  ln_kernel<<<M4 / 4, 256, 0, stream>>>(f4, ln2_g, ln2_b, pos4, NN4, XK, XV, nullptr);

  // ---- projections ----
  gemm_kernel<0, 512, 512, 512, 512, 4><<<(BDIM / 128) * (M3 / 128), 512, 65536, stream>>>(
      XQ, Wqt, bq, nullptr, QF);
  gemm_kernel<0, 512, 512, 512, 512, 4><<<(BDIM / 128) * (M4 / 128), 512, 65536, stream>>>(
      XK, Wkt, bk, nullptr, KF);
  gemm_kernel<0, 512, 512, 512, 512, 4><<<(BDIM / 128) * (M4 / 128), 512, 65536, stream>>>(
      XV, Wvt, bv, nullptr, VF);

  // ---- context (fused k-softmax) + att (fused q-softmax) ----
  ctx_kernel<<<NBATCH * NHEADS, 256, 0, stream>>>(KF, VF, CT);
  att_kernel<<<NBATCH * NHEADS, 256, 0, stream>>>(QF, CT, ATT);

  // ---- output projection: F3O(bf16) = f3(bf16 copy) + att @ Wr + br ----
  gemm_kernel<3, 512, 512, 512, 512, 4><<<(BDIM / 128) * (M3 / 128), 512, 65536, stream>>>(
      ATT, Wrt, br, F3B, F3O);

  // ---- LN3: YN(bf16) = ln(F3O) ----
  lnb_kernel<<<M3 / 4, 256, 0, stream>>>(F3O, ln3_g, ln3_b, YN);

  // ---- MLP, 2 row-chunks of 32768 ----
  for (int c = 0; c < 2; c++) {
    const bf16* Yc = YN + (size_t)c * MC * BDIM;
    const bf16* Fc = F3O + (size_t)c * MC * BDIM;
    float* outc = out + (size_t)c * MC * BDIM;
    gemm_kernel<1, 512, 512, 512, 2048, 16><<<(NMLP / 128) * (MC / 128), 512, 65536, stream>>>(
        Yc, W1t, b1, nullptr, H1);
    gemm_kernel<4, 2048, 2048, 2048, 512, 4><<<(BDIM / 128) * (MC / 128), 512, 65536, stream>>>(
        H1, W2t, b2, Fc, outc);
  }
}

// Round 19
// 747.729 us; speedup vs baseline: 1.0182x; 1.0182x over previous
//
#include <hip/hip_runtime.h>
#include <hip/hip_bf16.h>

typedef __attribute__((ext_vector_type(8))) short short8v;
typedef __attribute__((ext_vector_type(4))) float f32x4;
typedef __hip_bfloat16 bf16;

#define BDIM 512
#define NHEADS 8
#define DK 64
#define NBATCH 256
#define NN3 256
#define NN4 64
#define NMLP 2048

#define GLOAD_LDS16(g, l)                                                  \
  __builtin_amdgcn_global_load_lds(                                        \
      (const __attribute__((address_space(1))) void*)(g),                  \
      (__attribute__((address_space(3))) void*)(l), 16, 0, 0)

__device__ __forceinline__ float bf2f(short s) {
  union { short u[2]; float f; } cv;
  cv.u[0] = 0; cv.u[1] = s;
  return cv.f;
}
__device__ __forceinline__ short f2bf(float x) {
  bf16 h = __float2bfloat16(x);
  return *reinterpret_cast<short*>(&h);
}

// ------- coalesced transposing convert: Wt[n][k] = bf16(W[k][n]) ----------
__global__ __launch_bounds__(256) void convt_kernel(
    const float* __restrict__ W, bf16* __restrict__ Wt, int K, int N) {
  __shared__ float tile[32][33];
  int bx = blockIdx.x * 32, by = blockIdx.y * 32;
  int tx = threadIdx.x, ty = threadIdx.y;
#pragma unroll
  for (int j = 0; j < 32; j += 8)
    tile[ty + j][tx] = W[(size_t)(by + ty + j) * N + bx + tx];
  __syncthreads();
#pragma unroll
  for (int j = 0; j < 32; j += 8)
    Wt[(size_t)(bx + ty + j) * K + by + tx] = __float2bfloat16(tile[tx][ty + j]);
}

// ------- wave-per-row LayerNorm (f32 in), +pos, optional extra outs -------
__global__ __launch_bounds__(256) void ln_kernel(
    const float* __restrict__ x, const float* __restrict__ g,
    const float* __restrict__ beta, const float* __restrict__ pos, int nmod,
    bf16* __restrict__ out1, bf16* __restrict__ out2, bf16* __restrict__ raw) {
  int w = threadIdx.x >> 6, lane = threadIdx.x & 63;
  int row = blockIdx.x * 4 + w;
  int c0 = lane * 8;
  const float* xr = x + (size_t)row * BDIM + c0;
  float4 v0 = *(const float4*)xr;
  float4 v1 = *(const float4*)(xr + 4);
  float f[8] = {v0.x, v0.y, v0.z, v0.w, v1.x, v1.y, v1.z, v1.w};
  float s = 0.f, sq = 0.f;
#pragma unroll
  for (int i = 0; i < 8; i++) {
    s += f[i];
    sq += f[i] * f[i];
  }
#pragma unroll
  for (int o = 1; o <= 32; o <<= 1) {
    s += __shfl_xor(s, o);
    sq += __shfl_xor(sq, o);
  }
  float mean = s * (1.f / BDIM);
  float var = sq * (1.f / BDIM) - mean * mean;
  float rstd = rsqrtf(var + 1e-5f);
  float4 g0 = *(const float4*)(g + c0);
  float4 g1 = *(const float4*)(g + c0 + 4);
  float4 b0 = *(const float4*)(beta + c0);
  float4 b1 = *(const float4*)(beta + c0 + 4);
  float gg[8] = {g0.x, g0.y, g0.z, g0.w, g1.x, g1.y, g1.z, g1.w};
  float bb[8] = {b0.x, b0.y, b0.z, b0.w, b1.x, b1.y, b1.z, b1.w};
  float pv[8] = {};
  if (pos) {
    int n = row % nmod;
    const float* pr = pos + (size_t)n * BDIM + c0;
    float4 p0 = *(const float4*)pr;
    float4 p1 = *(const float4*)(pr + 4);
    pv[0] = p0.x; pv[1] = p0.y; pv[2] = p0.z; pv[3] = p0.w;
    pv[4] = p1.x; pv[5] = p1.y; pv[6] = p1.z; pv[7] = p1.w;
  }
  short8v o1, o2, rw;
#pragma unroll
  for (int i = 0; i < 8; i++) {
    float nv = (f[i] - mean) * rstd * gg[i] + bb[i];
    o1[i] = f2bf(nv + pv[i]);
    o2[i] = f2bf(nv);
    rw[i] = f2bf(f[i]);
  }
  size_t ob = (size_t)row * BDIM + c0;
  *(short8v*)(out1 + ob) = o1;
  if (out2) *(short8v*)(out2 + ob) = o2;
  if (raw) *(short8v*)(raw + ob) = rw;
}

// ---------- wave-per-row LayerNorm (bf16 in, bf16 out) --------------------
__global__ __launch_bounds__(256) void lnb_kernel(
    const bf16* __restrict__ x, const float* __restrict__ g,
    const float* __restrict__ beta, bf16* __restrict__ out) {
  int w = threadIdx.x >> 6, lane = threadIdx.x & 63;
  int row = blockIdx.x * 4 + w;
  int c0 = lane * 8;
  short8v v = *(const short8v*)(x + (size_t)row * BDIM + c0);
  float f[8];
  float s = 0.f, sq = 0.f;
#pragma unroll
  for (int i = 0; i < 8; i++) {
    f[i] = bf2f(v[i]);
    s += f[i];
    sq += f[i] * f[i];
  }
#pragma unroll
  for (int o = 1; o <= 32; o <<= 1) {
    s += __shfl_xor(s, o);
    sq += __shfl_xor(sq, o);
  }
  float mean = s * (1.f / BDIM);
  float var = sq * (1.f / BDIM) - mean * mean;
  float rstd = rsqrtf(var + 1e-5f);
  float4 g0 = *(const float4*)(g + c0);
  float4 g1 = *(const float4*)(g + c0 + 4);
  float4 b0 = *(const float4*)(beta + c0);
  float4 b1 = *(const float4*)(beta + c0 + 4);
  float gg[8] = {g0.x, g0.y, g0.z, g0.w, g1.x, g1.y, g1.z, g1.w};
  float bb[8] = {b0.x, b0.y, b0.z, b0.w, b1.x, b1.y, b1.z, b1.w};
  short8v o1;
#pragma unroll
  for (int i = 0; i < 8; i++) o1[i] = f2bf((f[i] - mean) * rstd * gg[i] + bb[i]);
  *(short8v*)(out + (size_t)row * BDIM + c0) = o1;
}

// ---------------- pipelined MFMA GEMM: out[M,N] = X[M,K] @ Wt[N,K]^T ------
// 128x128 tile, 8 waves (2x4), BK=64, 2 LDS buffers (64KB -> 2 blocks/CU),
// counted-vmcnt depth-2 prefetch, 2 raw barriers per K-step. [R17 champion,
// all dims compile-time -> full unroll + immediate-offset folding]
// EPI 0: bf16 out = acc + bias
// EPI 1: bf16 out = gelu_tanh(acc + bias)   (fast sigmoid form)
// EPI 3: bf16 out = srcbf16[o] + acc + bias
// EPI 4: f32  out = srcbf16[o] + acc + bias
template <int EPI, int K, int LDX, int LDW, int N, int GX>
__global__ __launch_bounds__(512) void gemm_kernel(
    const bf16* __restrict__ X, const bf16* __restrict__ Wt,
    const float* __restrict__ bias, const void* __restrict__ src, void* outp) {
  extern __shared__ bf16 lds[];  // 2 x 16384 elems = 64KB

  int nwg = gridDim.x;
  int cpx = nwg >> 3;
  int bid = blockIdx.x;
  int nb = (bid & 7) * cpx + (bid >> 3);
  int bx = nb % GX, by = nb / GX;
  int row0 = by * 128, col0 = bx * 128;

  int t = threadIdx.x, w = t >> 6, lane = t & 63;
  int wr = w >> 2, wc = w & 3;
  int r16 = lane & 15, kg = lane >> 4;
  int srow = lane >> 3;
  int scol = ((lane & 7) ^ srow) * 8;

  const bf16* gA0 = X + (size_t)(row0 + w * 16 + srow) * LDX + scol;
  const bf16* gB0 = Wt + (size_t)(col0 + w * 16 + srow) * LDW + scol;

  f32x4 acc[4][2] = {};

  auto stage = [&](int kt, int buf) {
    bf16* base = lds + buf * 16384;
    int ke = kt << 6;
#pragma unroll
    for (int j = 0; j < 2; j++) {
      GLOAD_LDS16(gA0 + ke + (size_t)j * 8 * LDX, base + (w * 16 + j * 8) * 64);
      GLOAD_LDS16(gB0 + ke + (size_t)j * 8 * LDW,
                  base + 8192 + (w * 16 + j * 8) * 64);
    }
  };

  auto compute = [&](int buf) {
    const char* base = (const char*)(lds + buf * 16384);
#pragma unroll
    for (int ksub = 0; ksub < 2; ksub++) {
      int cc = (ksub * 64 + kg * 16) ^ ((r16 & 7) << 4);
      short8v a[4], b[2];
#pragma unroll
      for (int m = 0; m < 4; m++)
        a[m] = *(const short8v*)(base + (wr * 64 + m * 16 + r16) * 128 + cc);
#pragma unroll
      for (int n = 0; n < 2; n++)
        b[n] = *(const short8v*)(base + 16384 + (wc * 32 + n * 16 + r16) * 128 + cc);
#pragma unroll
      for (int m = 0; m < 4; m++)
#pragma unroll
        for (int n = 0; n < 2; n++)
          acc[m][n] =
              __builtin_amdgcn_mfma_f32_16x16x32_bf16(a[m], b[n], acc[m][n], 0, 0, 0);
    }
  };

  constexpr int NT = K >> 6;
  stage(0, 0);
  stage(1, 1);
#pragma unroll
  for (int tt = 0; tt < NT; tt++) {
    if (tt < NT - 1)
      asm volatile("s_waitcnt vmcnt(4)" ::: "memory");
    else
      asm volatile("s_waitcnt vmcnt(0)" ::: "memory");
    __builtin_amdgcn_s_barrier();
    asm volatile("" ::: "memory");
    compute(tt & 1);
    asm volatile("" ::: "memory");
    __builtin_amdgcn_s_barrier();
    asm volatile("" ::: "memory");
    if (tt + 2 < NT) stage(tt + 2, tt & 1);
  }

#pragma unroll
  for (int n = 0; n < 2; n++) {
    int col = col0 + wc * 32 + n * 16 + r16;
    float bv = bias ? bias[col] : 0.f;
#pragma unroll
    for (int m = 0; m < 4; m++)
#pragma unroll
      for (int r = 0; r < 4; r++) {
        int row = row0 + wr * 64 + m * 16 + kg * 4 + r;
        size_t o = (size_t)row * N + col;
        float val = acc[m][n][r] + bv;
        if (EPI == 0) {
          ((bf16*)outp)[o] = __float2bfloat16(val);
        } else if (EPI == 1) {
          // gelu_tanh(x) = x * sigmoid(1.5957691*(x + 0.044715 x^3))
          float z = 1.5957691f * val * (1.f + 0.044715f * val * val);
          float gl = val / (1.f + __expf(-z));
          ((bf16*)outp)[o] = __float2bfloat16(gl);
        } else if (EPI == 3) {
          ((bf16*)outp)[o] = __float2bfloat16(bf2f(((const short*)src)[o]) + val);
        } else {
          ((float*)outp)[o] = bf2f(((const short*)src)[o]) + val;
        }
      }
  }
}

// ---- ctx: fused k-softmax (over positions) + ctxT[bh][vc][kc] einsum -----
__global__ __launch_bounds__(256) void ctx_kernel(
    const bf16* __restrict__ kproj, const bf16* __restrict__ vbuf,
    bf16* __restrict__ ctxT) {
  int bh = blockIdx.x;
  int b = bh >> 3, h = bh & 7;
  __shared__ bf16 lk[NN4][DK], lv[NN4][DK];
  int t = threadIdx.x;
#pragma unroll
  for (int i = 0; i < 16; i++) {
    int idx = i * 256 + t;
    int n = idx >> 6, c = idx & 63;
    size_t gaddr = (size_t)b * NN4 * BDIM + (size_t)n * BDIM + h * DK + c;
    lk[n][c] = kproj[gaddr];
    lv[n][c] = vbuf[gaddr];
  }
  __syncthreads();
  if (t < 64) {
    int c = t;
    float e[NN4];
    float m = -1e30f;
#pragma unroll
    for (int n = 0; n < NN4; n++) {
      e[n] = bf2f(*(short*)&lk[n][c]);
      m = fmaxf(m, e[n]);
    }
    float s = 0.f;
#pragma unroll
    for (int n = 0; n < NN4; n++) {
      e[n] = __expf(e[n] - m);
      s += e[n];
    }
    float inv = 1.f / s;
#pragma unroll
    for (int n = 0; n < NN4; n++) lk[n][c] = __float2bfloat16(e[n] * inv);
  }
  __syncthreads();
  int vc = t >> 2;
  int kc0 = (t & 3) * 16;
  float acc[16] = {};
  for (int n = 0; n < NN4; n++) {
    float vv = __bfloat162float(lv[n][vc]);
#pragma unroll
    for (int i = 0; i < 16; i++)
      acc[i] += vv * __bfloat162float(lk[n][kc0 + i]);
  }
  size_t o = (size_t)bh * 4096 + (size_t)vc * 64 + kc0;
#pragma unroll
  for (int i = 0; i < 16; i++) ctxT[o + i] = __float2bfloat16(acc[i]);
}

// ---- att: fused q-softmax (in-register, over 64 head channels) + GEMM ----
__global__ __launch_bounds__(256) void att_kernel(
    const bf16* __restrict__ qproj, const bf16* __restrict__ ctxT,
    bf16* __restrict__ att) {
  int bh = blockIdx.x;
  int b = bh >> 3, h = bh & 7;
  int t = threadIdx.x, w = t >> 6, lane = t & 63;
  int r16 = lane & 15, kg = lane >> 4;
  f32x4 acc[4][4] = {};
  const bf16* qb = qproj + (size_t)b * NN3 * BDIM + h * DK;
  const bf16* cb = ctxT + (size_t)bh * 4096;
  short8v bb[2][4];
#pragma unroll
  for (int kt = 0; kt < 2; kt++)
#pragma unroll
    for (int ni = 0; ni < 4; ni++)
      bb[kt][ni] = *(const short8v*)(cb + (ni * 16 + r16) * 64 + kt * 32 + kg * 8);
#pragma unroll
  for (int mi = 0; mi < 4; mi++) {
    int rrow = w * 64 + mi * 16 + r16;
    short8v a0 = *(const short8v*)(qb + (size_t)rrow * BDIM + kg * 8);
    short8v a1 = *(const short8v*)(qb + (size_t)rrow * BDIM + 32 + kg * 8);
    float f[16];
#pragma unroll
    for (int i = 0; i < 8; i++) {
      f[i] = bf2f(a0[i]);
      f[8 + i] = bf2f(a1[i]);
    }
    float m = f[0];
#pragma unroll
    for (int i = 1; i < 16; i++) m = fmaxf(m, f[i]);
    m = fmaxf(m, __shfl_xor(m, 16));
    m = fmaxf(m, __shfl_xor(m, 32));
    float s = 0.f;
#pragma unroll
    for (int i = 0; i < 16; i++) {
      f[i] = __expf(f[i] - m);
      s += f[i];
    }
    s += __shfl_xor(s, 16);
    s += __shfl_xor(s, 32);
    float inv = 1.f / s;
    short8v A0, A1;
#pragma unroll
    for (int i = 0; i < 8; i++) {
      A0[i] = f2bf(f[i] * inv);
      A1[i] = f2bf(f[8 + i] * inv);
    }
#pragma unroll
    for (int ni = 0; ni < 4; ni++) {
      acc[mi][ni] = __builtin_amdgcn_mfma_f32_16x16x32_bf16(A0, bb[0][ni], acc[mi][ni], 0, 0, 0);
      acc[mi][ni] = __builtin_amdgcn_mfma_f32_16x16x32_bf16(A1, bb[1][ni], acc[mi][ni], 0, 0, 0);
    }
  }
#pragma unroll
  for (int mi = 0; mi < 4; mi++)
#pragma unroll
    for (int ni = 0; ni < 4; ni++)
#pragma unroll
      for (int r = 0; r < 4; r++) {
        int row = w * 64 + mi * 16 + kg * 4 + r;
        int col = ni * 16 + r16;
        att[(size_t)(b * NN3 + row) * BDIM + h * DK + col] =
            __float2bfloat16(acc[mi][ni][r]);
      }
}

extern "C" void kernel_launch(void* const* d_in, const int* in_sizes, int n_in,
                              void* d_out, int out_size, void* d_ws, size_t ws_size,
                              hipStream_t stream) {
  const float* f3 = (const float*)d_in[0];
  const float* f4 = (const float*)d_in[1];
  const float* pos3 = (const float*)d_in[2];
  const float* pos4 = (const float*)d_in[3];
  const float* ln1_g = (const float*)d_in[4];
  const float* ln1_b = (const float*)d_in[5];
  const float* ln2_g = (const float*)d_in[6];
  const float* ln2_b = (const float*)d_in[7];
  const float* ln3_g = (const float*)d_in[8];
  const float* ln3_b = (const float*)d_in[9];
  const float* Wq = (const float*)d_in[10];
  const float* bq = (const float*)d_in[11];
  const float* Wk = (const float*)d_in[12];
  const float* bk = (const float*)d_in[13];
  const float* Wv = (const float*)d_in[14];
  const float* bv = (const float*)d_in[15];
  const float* Wr = (const float*)d_in[16];
  const float* br = (const float*)d_in[17];
  const float* W1 = (const float*)d_in[18];
  const float* b1 = (const float*)d_in[19];
  const float* W2 = (const float*)d_in[20];
  const float* b2 = (const float*)d_in[21];
  float* out = (float*)d_out;

  const int M3 = NBATCH * NN3;  // 65536
  const int M4 = NBATCH * NN4;  // 16384
  const int MC = M3 / 2;        // 32768 MLP row-chunk

  char* ws = (char*)d_ws;
  size_t off = 0;
  auto alloc = [&](size_t bytes) {
    size_t r = off;
    off = (off + bytes + 255) & ~(size_t)255;
    return r;
  };
  size_t oWqt = alloc((size_t)BDIM * BDIM * 2);
  size_t oWkt = alloc((size_t)BDIM * BDIM * 2);
  size_t oWvt = alloc((size_t)BDIM * BDIM * 2);
  size_t oWrt = alloc((size_t)BDIM * BDIM * 2);
  size_t oW1t = alloc((size_t)BDIM * NMLP * 2);
  size_t oW2t = alloc((size_t)BDIM * NMLP * 2);
  size_t oXQ = alloc((size_t)M3 * BDIM * 2);  // ln(f3)+pos3 -> att -> Yn
  size_t oXK = alloc((size_t)M4 * BDIM * 2);
  size_t oXV = alloc((size_t)M4 * BDIM * 2);
  size_t oQF = alloc((size_t)M3 * BDIM * 2);  // q proj -> F3O
  size_t oKF = alloc((size_t)M4 * BDIM * 2);
  size_t oVF = alloc((size_t)M4 * BDIM * 2);
  size_t oF3B = alloc((size_t)M3 * BDIM * 2);  // bf16 copy of f3
  size_t oCT = alloc((size_t)NBATCH * NHEADS * DK * DK * 2);
  size_t oH1 = alloc((size_t)MC * NMLP * 2);  // 128MB hidden row-chunk
  (void)ws_size;

  bf16* Wqt = (bf16*)(ws + oWqt);
  bf16* Wkt = (bf16*)(ws + oWkt);
  bf16* Wvt = (bf16*)(ws + oWvt);
  bf16* Wrt = (bf16*)(ws + oWrt);
  bf16* W1t = (bf16*)(ws + oW1t);
  bf16* W2t = (bf16*)(ws + oW2t);
  bf16* XQ = (bf16*)(ws + oXQ);
  bf16* XK = (bf16*)(ws + oXK);
  bf16* XV = (bf16*)(ws + oXV);
  bf16* QF = (bf16*)(ws + oQF);
  bf16* KF = (bf16*)(ws + oKF);
  bf16* VF = (bf16*)(ws + oVF);
  bf16* F3B = (bf16*)(ws + oF3B);
  bf16* CT = (bf16*)(ws + oCT);
  bf16* H1 = (bf16*)(ws + oH1);
  bf16* ATT = XQ;   // reuse (XQ dead after q projection)
  bf16* F3O = QF;   // reuse (QF dead after att)
  bf16* YN = XQ;    // reuse (ATT dead after outproj)

  // dynamic-LDS caps for the 4 GEMM instantiations
  hipFuncSetAttribute((const void*)gemm_kernel<0, 512, 512, 512, 512, 4>,
                      hipFuncAttributeMaxDynamicSharedMemorySize, 65536);
  hipFuncSetAttribute((const void*)gemm_kernel<1, 512, 512, 512, 2048, 16>,
                      hipFuncAttributeMaxDynamicSharedMemorySize, 65536);
  hipFuncSetAttribute((const void*)gemm_kernel<3, 512, 512, 512, 512, 4>,
                      hipFuncAttributeMaxDynamicSharedMemorySize, 65536);
  hipFuncSetAttribute((const void*)gemm_kernel<4, 2048, 2048, 2048, 512, 4>,
                      hipFuncAttributeMaxDynamicSharedMemorySize, 65536);

  // ---- weight conversion (coalesced LDS-tile transpose) ----
  convt_kernel<<<dim3(BDIM / 32, BDIM / 32), dim3(32, 8), 0, stream>>>(Wq, Wqt, BDIM, BDIM);
  convt_kernel<<<dim3(BDIM / 32, BDIM / 32), dim3(32, 8), 0, stream>>>(Wk, Wkt, BDIM, BDIM);
  convt_kernel<<<dim3(BDIM / 32, BDIM / 32), dim3(32, 8), 0, stream>>>(Wv, Wvt, BDIM, BDIM);
  convt_kernel<<<dim3(BDIM / 32, BDIM / 32), dim3(32, 8), 0, stream>>>(Wr, Wrt, BDIM, BDIM);
  convt_kernel<<<dim3(NMLP / 32, BDIM / 32), dim3(32, 8), 0, stream>>>(W1, W1t, BDIM, NMLP);
  convt_kernel<<<dim3(BDIM / 32, NMLP / 32), dim3(32, 8), 0, stream>>>(W2, W2t, NMLP, BDIM);

  // ---- layernorms (f3 pass also emits bf16 raw copy for residual) ----
  ln_kernel<<<M3 / 4, 256, 0, stream>>>(f3, ln1_g, ln1_b, pos3, NN3, XQ, nullptr, F3B);
  ln_kernel<<<M4 / 4, 256, 0, stream>>>(f4, ln2_g, ln2_b, pos4, NN4, XK, XV, nullptr);

  // ---- projections ----
  gemm_kernel<0, 512, 512, 512, 512, 4><<<(BDIM / 128) * (M3 / 128), 512, 65536, stream>>>(
      XQ, Wqt, bq, nullptr, QF);
  gemm_kernel<0, 512, 512, 512, 512, 4><<<(BDIM / 128) * (M4 / 128), 512, 65536, stream>>>(
      XK, Wkt, bk, nullptr, KF);
  gemm_kernel<0, 512, 512, 512, 512, 4><<<(BDIM / 128) * (M4 / 128), 512, 65536, stream>>>(
      XV, Wvt, bv, nullptr, VF);

  // ---- context (fused k-softmax) + att (fused q-softmax) ----
  ctx_kernel<<<NBATCH * NHEADS, 256, 0, stream>>>(KF, VF, CT);
  att_kernel<<<NBATCH * NHEADS, 256, 0, stream>>>(QF, CT, ATT);

  // ---- output projection: F3O(bf16) = f3(bf16 copy) + att @ Wr + br ----
  gemm_kernel<3, 512, 512, 512, 512, 4><<<(BDIM / 128) * (M3 / 128), 512, 65536, stream>>>(
      ATT, Wrt, br, F3B, F3O);

  // ---- LN3: YN(bf16) = ln(F3O) ----
  lnb_kernel<<<M3 / 4, 256, 0, stream>>>(F3O, ln3_g, ln3_b, YN);

  // ---- MLP, 2 row-chunks of 32768 ----
  for (int c = 0; c < 2; c++) {
    const bf16* Yc = YN + (size_t)c * MC * BDIM;
    const bf16* Fc = F3O + (size_t)c * MC * BDIM;
    float* outc = out + (size_t)c * MC * BDIM;
    gemm_kernel<1, 512, 512, 512, 2048, 16><<<(NMLP / 128) * (MC / 128), 512, 65536, stream>>>(
        Yc, W1t, b1, nullptr, H1);
    gemm_kernel<4, 2048, 2048, 2048, 512, 4><<<(BDIM / 128) * (MC / 128), 512, 65536, stream>>>(
        H1, W2t, b2, Fc, outc);
  }
}

// Round 20
// 747.415 us; speedup vs baseline: 1.0186x; 1.0004x over previous
//
#include <hip/hip_runtime.h>
#include <hip/hip_bf16.h>

typedef __attribute__((ext_vector_type(8))) short short8v;
typedef __attribute__((ext_vector_type(4))) float f32x4;
typedef __hip_bfloat16 bf16;

#define BDIM 512
#define NHEADS 8
#define DK 64
#define NBATCH 256
#define NN3 256
#define NN4 64
#define NMLP 2048

#define GLOAD_LDS16(g, l)                                                  \
  __builtin_amdgcn_global_load_lds(                                        \
      (const __attribute__((address_space(1))) void*)(g),                  \
      (__attribute__((address_space(3))) void*)(l), 16, 0, 0)

__device__ __forceinline__ float bf2f(short s) {
  union { short u[2]; float f; } cv;
  cv.u[0] = 0; cv.u[1] = s;
  return cv.f;
}
__device__ __forceinline__ short f2bf(float x) {
  bf16 h = __float2bfloat16(x);
  return *reinterpret_cast<short*>(&h);
}

// ------- coalesced transposing convert: Wt[n][k] = bf16(W[k][n]) ----------
__global__ __launch_bounds__(256) void convt_kernel(
    const float* __restrict__ W, bf16* __restrict__ Wt, int K, int N) {
  __shared__ float tile[32][33];
  int bx = blockIdx.x * 32, by = blockIdx.y * 32;
  int tx = threadIdx.x, ty = threadIdx.y;
#pragma unroll
  for (int j = 0; j < 32; j += 8)
    tile[ty + j][tx] = W[(size_t)(by + ty + j) * N + bx + tx];
  __syncthreads();
#pragma unroll
  for (int j = 0; j < 32; j += 8)
    Wt[(size_t)(bx + ty + j) * K + by + tx] = __float2bfloat16(tile[tx][ty + j]);
}

// ------- wave-per-row LayerNorm (f32 in), +pos, optional extra outs -------
__global__ __launch_bounds__(256) void ln_kernel(
    const float* __restrict__ x, const float* __restrict__ g,
    const float* __restrict__ beta, const float* __restrict__ pos, int nmod,
    bf16* __restrict__ out1, bf16* __restrict__ out2, bf16* __restrict__ raw) {
  int w = threadIdx.x >> 6, lane = threadIdx.x & 63;
  int row = blockIdx.x * 4 + w;
  int c0 = lane * 8;
  const float* xr = x + (size_t)row * BDIM + c0;
  float4 v0 = *(const float4*)xr;
  float4 v1 = *(const float4*)(xr + 4);
  float f[8] = {v0.x, v0.y, v0.z, v0.w, v1.x, v1.y, v1.z, v1.w};
  float s = 0.f, sq = 0.f;
#pragma unroll
  for (int i = 0; i < 8; i++) {
    s += f[i];
    sq += f[i] * f[i];
  }
#pragma unroll
  for (int o = 1; o <= 32; o <<= 1) {
    s += __shfl_xor(s, o);
    sq += __shfl_xor(sq, o);
  }
  float mean = s * (1.f / BDIM);
  float var = sq * (1.f / BDIM) - mean * mean;
  float rstd = rsqrtf(var + 1e-5f);
  float4 g0 = *(const float4*)(g + c0);
  float4 g1 = *(const float4*)(g + c0 + 4);
  float4 b0 = *(const float4*)(beta + c0);
  float4 b1 = *(const float4*)(beta + c0 + 4);
  float gg[8] = {g0.x, g0.y, g0.z, g0.w, g1.x, g1.y, g1.z, g1.w};
  float bb[8] = {b0.x, b0.y, b0.z, b0.w, b1.x, b1.y, b1.z, b1.w};
  float pv[8] = {};
  if (pos) {
    int n = row % nmod;
    const float* pr = pos + (size_t)n * BDIM + c0;
    float4 p0 = *(const float4*)pr;
    float4 p1 = *(const float4*)(pr + 4);
    pv[0] = p0.x; pv[1] = p0.y; pv[2] = p0.z; pv[3] = p0.w;
    pv[4] = p1.x; pv[5] = p1.y; pv[6] = p1.z; pv[7] = p1.w;
  }
  short8v o1, o2, rw;
#pragma unroll
  for (int i = 0; i < 8; i++) {
    float nv = (f[i] - mean) * rstd * gg[i] + bb[i];
    o1[i] = f2bf(nv + pv[i]);
    o2[i] = f2bf(nv);
    rw[i] = f2bf(f[i]);
  }
  size_t ob = (size_t)row * BDIM + c0;
  *(short8v*)(out1 + ob) = o1;
  if (out2) *(short8v*)(out2 + ob) = o2;
  if (raw) *(short8v*)(raw + ob) = rw;
}

// ---------- wave-per-row LayerNorm (bf16 in, bf16 out) --------------------
__global__ __launch_bounds__(256) void lnb_kernel(
    const bf16* __restrict__ x, const float* __restrict__ g,
    const float* __restrict__ beta, bf16* __restrict__ out) {
  int w = threadIdx.x >> 6, lane = threadIdx.x & 63;
  int row = blockIdx.x * 4 + w;
  int c0 = lane * 8;
  short8v v = *(const short8v*)(x + (size_t)row * BDIM + c0);
  float f[8];
  float s = 0.f, sq = 0.f;
#pragma unroll
  for (int i = 0; i < 8; i++) {
    f[i] = bf2f(v[i]);
    s += f[i];
    sq += f[i] * f[i];
  }
#pragma unroll
  for (int o = 1; o <= 32; o <<= 1) {
    s += __shfl_xor(s, o);
    sq += __shfl_xor(sq, o);
  }
  float mean = s * (1.f / BDIM);
  float var = sq * (1.f / BDIM) - mean * mean;
  float rstd = rsqrtf(var + 1e-5f);
  float4 g0 = *(const float4*)(g + c0);
  float4 g1 = *(const float4*)(g + c0 + 4);
  float4 b0 = *(const float4*)(beta + c0);
  float4 b1 = *(const float4*)(beta + c0 + 4);
  float gg[8] = {g0.x, g0.y, g0.z, g0.w, g1.x, g1.y, g1.z, g1.w};
  float bb[8] = {b0.x, b0.y, b0.z, b0.w, b1.x, b1.y, b1.z, b1.w};
  short8v o1;
#pragma unroll
  for (int i = 0; i < 8; i++) o1[i] = f2bf((f[i] - mean) * rstd * gg[i] + bb[i]);
  *(short8v*)(out + (size_t)row * BDIM + c0) = o1;
}

// ---------------- pipelined MFMA GEMM: out[M,N] = X[M,K] @ Wt[N,K]^T ------
// 128x128 tile, 8 waves (2x4), BK=64, 2 LDS buffers (64KB -> 2 blocks/CU),
// counted-vmcnt depth-2 prefetch, 2 raw barriers per K-step. [R17 champion,
// all dims compile-time -> full unroll + immediate-offset folding]
// EPI 0: bf16 out = acc + bias
// EPI 1: bf16 out = gelu_tanh(acc + bias)   (fast sigmoid form)
// EPI 3: bf16 out = srcbf16[o] + acc + bias
// EPI 4: f32  out = srcbf16[o] + acc + bias
template <int EPI, int K, int LDX, int LDW, int N, int GX>
__global__ __launch_bounds__(512) void gemm_kernel(
    const bf16* __restrict__ X, const bf16* __restrict__ Wt,
    const float* __restrict__ bias, const void* __restrict__ src, void* outp) {
  extern __shared__ bf16 lds[];  // 2 x 16384 elems = 64KB

  int nwg = gridDim.x;
  int cpx = nwg >> 3;
  int bid = blockIdx.x;
  int nb = (bid & 7) * cpx + (bid >> 3);
  int bx = nb % GX, by = nb / GX;
  int row0 = by * 128, col0 = bx * 128;

  int t = threadIdx.x, w = t >> 6, lane = t & 63;
  int wr = w >> 2, wc = w & 3;
  int r16 = lane & 15, kg = lane >> 4;
  int srow = lane >> 3;
  int scol = ((lane & 7) ^ srow) * 8;

  const bf16* gA0 = X + (size_t)(row0 + w * 16 + srow) * LDX + scol;
  const bf16* gB0 = Wt + (size_t)(col0 + w * 16 + srow) * LDW + scol;

  f32x4 acc[4][2] = {};

  auto stage = [&](int kt, int buf) {
    bf16* base = lds + buf * 16384;
    int ke = kt << 6;
#pragma unroll
    for (int j = 0; j < 2; j++) {
      GLOAD_LDS16(gA0 + ke + (size_t)j * 8 * LDX, base + (w * 16 + j * 8) * 64);
      GLOAD_LDS16(gB0 + ke + (size_t)j * 8 * LDW,
                  base + 8192 + (w * 16 + j * 8) * 64);
    }
  };

  auto compute = [&](int buf) {
    const char* base = (const char*)(lds + buf * 16384);
#pragma unroll
    for (int ksub = 0; ksub < 2; ksub++) {
      int cc = (ksub * 64 + kg * 16) ^ ((r16 & 7) << 4);
      short8v a[4], b[2];
#pragma unroll
      for (int m = 0; m < 4; m++)
        a[m] = *(const short8v*)(base + (wr * 64 + m * 16 + r16) * 128 + cc);
#pragma unroll
      for (int n = 0; n < 2; n++)
        b[n] = *(const short8v*)(base + 16384 + (wc * 32 + n * 16 + r16) * 128 + cc);
#pragma unroll
      for (int m = 0; m < 4; m++)
#pragma unroll
        for (int n = 0; n < 2; n++)
          acc[m][n] =
              __builtin_amdgcn_mfma_f32_16x16x32_bf16(a[m], b[n], acc[m][n], 0, 0, 0);
    }
  };

  constexpr int NT = K >> 6;
  stage(0, 0);
  stage(1, 1);
#pragma unroll
  for (int tt = 0; tt < NT; tt++) {
    if (tt < NT - 1)
      asm volatile("s_waitcnt vmcnt(4)" ::: "memory");
    else
      asm volatile("s_waitcnt vmcnt(0)" ::: "memory");
    __builtin_amdgcn_s_barrier();
    asm volatile("" ::: "memory");
    compute(tt & 1);
    asm volatile("" ::: "memory");
    __builtin_amdgcn_s_barrier();
    asm volatile("" ::: "memory");
    if (tt + 2 < NT) stage(tt + 2, tt & 1);
  }

#pragma unroll
  for (int n = 0; n < 2; n++) {
    int col = col0 + wc * 32 + n * 16 + r16;
    float bv = bias ? bias[col] : 0.f;
#pragma unroll
    for (int m = 0; m < 4; m++)
#pragma unroll
      for (int r = 0; r < 4; r++) {
        int row = row0 + wr * 64 + m * 16 + kg * 4 + r;
        size_t o = (size_t)row * N + col;
        float val = acc[m][n][r] + bv;
        if (EPI == 0) {
          ((bf16*)outp)[o] = __float2bfloat16(val);
        } else if (EPI == 1) {
          // gelu_tanh(x) = x * sigmoid(1.5957691*(x + 0.044715 x^3))
          float z = 1.5957691f * val * (1.f + 0.044715f * val * val);
          float gl = val / (1.f + __expf(-z));
          ((bf16*)outp)[o] = __float2bfloat16(gl);
        } else if (EPI == 3) {
          ((bf16*)outp)[o] = __float2bfloat16(bf2f(((const short*)src)[o]) + val);
        } else {
          ((float*)outp)[o] = bf2f(((const short*)src)[o]) + val;
        }
      }
  }
}

// ---- ctx: fused k-softmax (over positions) + ctxT[bh][vc][kc] einsum -----
__global__ __launch_bounds__(256) void ctx_kernel(
    const bf16* __restrict__ kproj, const bf16* __restrict__ vbuf,
    bf16* __restrict__ ctxT) {
  int bh = blockIdx.x;
  int b = bh >> 3, h = bh & 7;
  __shared__ bf16 lk[NN4][DK], lv[NN4][DK];
  int t = threadIdx.x;
#pragma unroll
  for (int i = 0; i < 16; i++) {
    int idx = i * 256 + t;
    int n = idx >> 6, c = idx & 63;
    size_t gaddr = (size_t)b * NN4 * BDIM + (size_t)n * BDIM + h * DK + c;
    lk[n][c] = kproj[gaddr];
    lv[n][c] = vbuf[gaddr];
  }
  __syncthreads();
  if (t < 64) {
    int c = t;
    float e[NN4];
    float m = -1e30f;
#pragma unroll
    for (int n = 0; n < NN4; n++) {
      e[n] = bf2f(*(short*)&lk[n][c]);
      m = fmaxf(m, e[n]);
    }
    float s = 0.f;
#pragma unroll
    for (int n = 0; n < NN4; n++) {
      e[n] = __expf(e[n] - m);
      s += e[n];
    }
    float inv = 1.f / s;
#pragma unroll
    for (int n = 0; n < NN4; n++) lk[n][c] = __float2bfloat16(e[n] * inv);
  }
  __syncthreads();
  int vc = t >> 2;
  int kc0 = (t & 3) * 16;
  float acc[16] = {};
  for (int n = 0; n < NN4; n++) {
    float vv = __bfloat162float(lv[n][vc]);
#pragma unroll
    for (int i = 0; i < 16; i++)
      acc[i] += vv * __bfloat162float(lk[n][kc0 + i]);
  }
  size_t o = (size_t)bh * 4096 + (size_t)vc * 64 + kc0;
#pragma unroll
  for (int i = 0; i < 16; i++) ctxT[o + i] = __float2bfloat16(acc[i]);
}

// ---- att: fused q-softmax (in-register, over 64 head channels) + GEMM ----
__global__ __launch_bounds__(256) void att_kernel(
    const bf16* __restrict__ qproj, const bf16* __restrict__ ctxT,
    bf16* __restrict__ att) {
  int bh = blockIdx.x;
  int b = bh >> 3, h = bh & 7;
  int t = threadIdx.x, w = t >> 6, lane = t & 63;
  int r16 = lane & 15, kg = lane >> 4;
  f32x4 acc[4][4] = {};
  const bf16* qb = qproj + (size_t)b * NN3 * BDIM + h * DK;
  const bf16* cb = ctxT + (size_t)bh * 4096;
  short8v bb[2][4];
#pragma unroll
  for (int kt = 0; kt < 2; kt++)
#pragma unroll
    for (int ni = 0; ni < 4; ni++)
      bb[kt][ni] = *(const short8v*)(cb + (ni * 16 + r16) * 64 + kt * 32 + kg * 8);
#pragma unroll
  for (int mi = 0; mi < 4; mi++) {
    int rrow = w * 64 + mi * 16 + r16;
    short8v a0 = *(const short8v*)(qb + (size_t)rrow * BDIM + kg * 8);
    short8v a1 = *(const short8v*)(qb + (size_t)rrow * BDIM + 32 + kg * 8);
    float f[16];
#pragma unroll
    for (int i = 0; i < 8; i++) {
      f[i] = bf2f(a0[i]);
      f[8 + i] = bf2f(a1[i]);
    }
    float m = f[0];
#pragma unroll
    for (int i = 1; i < 16; i++) m = fmaxf(m, f[i]);
    m = fmaxf(m, __shfl_xor(m, 16));
    m = fmaxf(m, __shfl_xor(m, 32));
    float s = 0.f;
#pragma unroll
    for (int i = 0; i < 16; i++) {
      f[i] = __expf(f[i] - m);
      s += f[i];
    }
    s += __shfl_xor(s, 16);
    s += __shfl_xor(s, 32);
    float inv = 1.f / s;
    short8v A0, A1;
#pragma unroll
    for (int i = 0; i < 8; i++) {
      A0[i] = f2bf(f[i] * inv);
      A1[i] = f2bf(f[8 + i] * inv);
    }
#pragma unroll
    for (int ni = 0; ni < 4; ni++) {
      acc[mi][ni] = __builtin_amdgcn_mfma_f32_16x16x32_bf16(A0, bb[0][ni], acc[mi][ni], 0, 0, 0);
      acc[mi][ni] = __builtin_amdgcn_mfma_f32_16x16x32_bf16(A1, bb[1][ni], acc[mi][ni], 0, 0, 0);
    }
  }
#pragma unroll
  for (int mi = 0; mi < 4; mi++)
#pragma unroll
    for (int ni = 0; ni < 4; ni++)
#pragma unroll
      for (int r = 0; r < 4; r++) {
        int row = w * 64 + mi * 16 + kg * 4 + r;
        int col = ni * 16 + r16;
        att[(size_t)(b * NN3 + row) * BDIM + h * DK + col] =
            __float2bfloat16(acc[mi][ni][r]);
      }
}

extern "C" void kernel_launch(void* const* d_in, const int* in_sizes, int n_in,
                              void* d_out, int out_size, void* d_ws, size_t ws_size,
                              hipStream_t stream) {
  const float* f3 = (const float*)d_in[0];
  const float* f4 = (const float*)d_in[1];
  const float* pos3 = (const float*)d_in[2];
  const float* pos4 = (const float*)d_in[3];
  const float* ln1_g = (const float*)d_in[4];
  const float* ln1_b = (const float*)d_in[5];
  const float* ln2_g = (const float*)d_in[6];
  const float* ln2_b = (const float*)d_in[7];
  const float* ln3_g = (const float*)d_in[8];
  const float* ln3_b = (const float*)d_in[9];
  const float* Wq = (const float*)d_in[10];
  const float* bq = (const float*)d_in[11];
  const float* Wk = (const float*)d_in[12];
  const float* bk = (const float*)d_in[13];
  const float* Wv = (const float*)d_in[14];
  const float* bv = (const float*)d_in[15];
  const float* Wr = (const float*)d_in[16];
  const float* br = (const float*)d_in[17];
  const float* W1 = (const float*)d_in[18];
  const float* b1 = (const float*)d_in[19];
  const float* W2 = (const float*)d_in[20];
  const float* b2 = (const float*)d_in[21];
  float* out = (float*)d_out;

  const int M3 = NBATCH * NN3;  // 65536
  const int M4 = NBATCH * NN4;  // 16384
  const int MC = M3 / 4;        // 16384 MLP row-chunk (H1 = 64MB, L3-resident)

  char* ws = (char*)d_ws;
  size_t off = 0;
  auto alloc = [&](size_t bytes) {
    size_t r = off;
    off = (off + bytes + 255) & ~(size_t)255;
    return r;
  };
  size_t oWqt = alloc((size_t)BDIM * BDIM * 2);
  size_t oWkt = alloc((size_t)BDIM * BDIM * 2);
  size_t oWvt = alloc((size_t)BDIM * BDIM * 2);
  size_t oWrt = alloc((size_t)BDIM * BDIM * 2);
  size_t oW1t = alloc((size_t)BDIM * NMLP * 2);
  size_t oW2t = alloc((size_t)BDIM * NMLP * 2);
  size_t oXQ = alloc((size_t)M3 * BDIM * 2);  // ln(f3)+pos3 -> att -> Yn
  size_t oXK = alloc((size_t)M4 * BDIM * 2);
  size_t oXV = alloc((size_t)M4 * BDIM * 2);
  size_t oQF = alloc((size_t)M3 * BDIM * 2);  // q proj -> F3O
  size_t oKF = alloc((size_t)M4 * BDIM * 2);
  size_t oVF = alloc((size_t)M4 * BDIM * 2);
  size_t oF3B = alloc((size_t)M3 * BDIM * 2);  // bf16 copy of f3
  size_t oCT = alloc((size_t)NBATCH * NHEADS * DK * DK * 2);
  size_t oH1 = alloc((size_t)MC * NMLP * 2);  // 64MB hidden row-chunk
  (void)ws_size;

  bf16* Wqt = (bf16*)(ws + oWqt);
  bf16* Wkt = (bf16*)(ws + oWkt);
  bf16* Wvt = (bf16*)(ws + oWvt);
  bf16* Wrt = (bf16*)(ws + oWrt);
  bf16* W1t = (bf16*)(ws + oW1t);
  bf16* W2t = (bf16*)(ws + oW2t);
  bf16* XQ = (bf16*)(ws + oXQ);
  bf16* XK = (bf16*)(ws + oXK);
  bf16* XV = (bf16*)(ws + oXV);
  bf16* QF = (bf16*)(ws + oQF);
  bf16* KF = (bf16*)(ws + oKF);
  bf16* VF = (bf16*)(ws + oVF);
  bf16* F3B = (bf16*)(ws + oF3B);
  bf16* CT = (bf16*)(ws + oCT);
  bf16* H1 = (bf16*)(ws + oH1);
  bf16* ATT = XQ;   // reuse (XQ dead after q projection)
  bf16* F3O = QF;   // reuse (QF dead after att)
  bf16* YN = XQ;    // reuse (ATT dead after outproj)

  // dynamic-LDS caps for the 4 GEMM instantiations
  hipFuncSetAttribute((const void*)gemm_kernel<0, 512, 512, 512, 512, 4>,
                      hipFuncAttributeMaxDynamicSharedMemorySize, 65536);
  hipFuncSetAttribute((const void*)gemm_kernel<1, 512, 512, 512, 2048, 16>,
                      hipFuncAttributeMaxDynamicSharedMemorySize, 65536);
  hipFuncSetAttribute((const void*)gemm_kernel<3, 512, 512, 512, 512, 4>,
                      hipFuncAttributeMaxDynamicSharedMemorySize, 65536);
  hipFuncSetAttribute((const void*)gemm_kernel<4, 2048, 2048, 2048, 512, 4>,
                      hipFuncAttributeMaxDynamicSharedMemorySize, 65536);

  // ---- weight conversion (coalesced LDS-tile transpose) ----
  convt_kernel<<<dim3(BDIM / 32, BDIM / 32), dim3(32, 8), 0, stream>>>(Wq, Wqt, BDIM, BDIM);
  convt_kernel<<<dim3(BDIM / 32, BDIM / 32), dim3(32, 8), 0, stream>>>(Wk, Wkt, BDIM, BDIM);
  convt_kernel<<<dim3(BDIM / 32, BDIM / 32), dim3(32, 8), 0, stream>>>(Wv, Wvt, BDIM, BDIM);
  convt_kernel<<<dim3(BDIM / 32, BDIM / 32), dim3(32, 8), 0, stream>>>(Wr, Wrt, BDIM, BDIM);
  convt_kernel<<<dim3(NMLP / 32, BDIM / 32), dim3(32, 8), 0, stream>>>(W1, W1t, BDIM, NMLP);
  convt_kernel<<<dim3(BDIM / 32, NMLP / 32), dim3(32, 8), 0, stream>>>(W2, W2t, NMLP, BDIM);

  // ---- layernorms (f3 pass also emits bf16 raw copy for residual) ----
  ln_kernel<<<M3 / 4, 256, 0, stream>>>(f3, ln1_g, ln1_b, pos3, NN3, XQ, nullptr, F3B);
  ln_kernel<<<M4 / 4, 256, 0, stream>>>(f4, ln2_g, ln2_b, pos4, NN4, XK, XV, nullptr);

  // ---- projections ----
  gemm_kernel<0, 512, 512, 512, 512, 4><<<(BDIM / 128) * (M3 / 128), 512, 65536, stream>>>(
      XQ, Wqt, bq, nullptr, QF);
  gemm_kernel<0, 512, 512, 512, 512, 4><<<(BDIM / 128) * (M4 / 128), 512, 65536, stream>>>(
      XK, Wkt, bk, nullptr, KF);
  gemm_kernel<0, 512, 512, 512, 512, 4><<<(BDIM / 128) * (M4 / 128), 512, 65536, stream>>>(
      XV, Wvt, bv, nullptr, VF);

  // ---- context (fused k-softmax) + att (fused q-softmax) ----
  ctx_kernel<<<NBATCH * NHEADS, 256, 0, stream>>>(KF, VF, CT);
  att_kernel<<<NBATCH * NHEADS, 256, 0, stream>>>(QF, CT, ATT);

  // ---- output projection: F3O(bf16) = f3(bf16 copy) + att @ Wr + br ----
  gemm_kernel<3, 512, 512, 512, 512, 4><<<(BDIM / 128) * (M3 / 128), 512, 65536, stream>>>(
      ATT, Wrt, br, F3B, F3O);

  // ---- LN3: YN(bf16) = ln(F3O) ----
  lnb_kernel<<<M3 / 4, 256, 0, stream>>>(F3O, ln3_g, ln3_b, YN);

  // ---- MLP, 4 row-chunks of 16384 (H1 chunk 64MB -> L3-resident) ----
  for (int c = 0; c < 4; c++) {
    const bf16* Yc = YN + (size_t)c * MC * BDIM;
    const bf16* Fc = F3O + (size_t)c * MC * BDIM;
    float* outc = out + (size_t)c * MC * BDIM;
    gemm_kernel<1, 512, 512, 512, 2048, 16><<<(NMLP / 128) * (MC / 128), 512, 65536, stream>>>(
        Yc, W1t, b1, nullptr, H1);
    gemm_kernel<4, 2048, 2048, 2048, 512, 4><<<(BDIM / 128) * (MC / 128), 512, 65536, stream>>>(
        H1, W2t, b2, Fc, outc);
  }
}

// Round 21
// 730.181 us; speedup vs baseline: 1.0427x; 1.0236x over previous
//
#include <hip/hip_runtime.h>
#include <hip/hip_bf16.h>

typedef __attribute__((ext_vector_type(8))) short short8v;
typedef __attribute__((ext_vector_type(4))) float f32x4;
typedef __hip_bfloat16 bf16;

#define BDIM 512
#define NHEADS 8
#define DK 64
#define NBATCH 256
#define NN3 256
#define NN4 64
#define NMLP 2048

#define GLOAD_LDS16(g, l)                                                  \
  __builtin_amdgcn_global_load_lds(                                        \
      (const __attribute__((address_space(1))) void*)(g),                  \
      (__attribute__((address_space(3))) void*)(l), 16, 0, 0)

__device__ __forceinline__ float bf2f(short s) {
  union { short u[2]; float f; } cv;
  cv.u[0] = 0; cv.u[1] = s;
  return cv.f;
}
__device__ __forceinline__ short f2bf(float x) {
  bf16 h = __float2bfloat16(x);
  return *reinterpret_cast<short*>(&h);
}

// ------- coalesced transposing convert: Wt[n][k] = bf16(W[k][n]) ----------
__global__ __launch_bounds__(256) void convt_kernel(
    const float* __restrict__ W, bf16* __restrict__ Wt, int K, int N) {
  __shared__ float tile[32][33];
  int bx = blockIdx.x * 32, by = blockIdx.y * 32;
  int tx = threadIdx.x, ty = threadIdx.y;
#pragma unroll
  for (int j = 0; j < 32; j += 8)
    tile[ty + j][tx] = W[(size_t)(by + ty + j) * N + bx + tx];
  __syncthreads();
#pragma unroll
  for (int j = 0; j < 32; j += 8)
    Wt[(size_t)(bx + ty + j) * K + by + tx] = __float2bfloat16(tile[tx][ty + j]);
}

// ------- batched 512x512 transposing convert (4 weights in one launch) ----
__global__ __launch_bounds__(256) void convt4_kernel(
    const float* __restrict__ W0, const float* __restrict__ W1,
    const float* __restrict__ W2, const float* __restrict__ W3,
    bf16* __restrict__ O0, bf16* __restrict__ O1, bf16* __restrict__ O2,
    bf16* __restrict__ O3) {
  __shared__ float tile[32][33];
  const float* W;
  bf16* O;
  switch (blockIdx.z) {
    case 0: W = W0; O = O0; break;
    case 1: W = W1; O = O1; break;
    case 2: W = W2; O = O2; break;
    default: W = W3; O = O3; break;
  }
  int bx = blockIdx.x * 32, by = blockIdx.y * 32;
  int tx = threadIdx.x, ty = threadIdx.y;
#pragma unroll
  for (int j = 0; j < 32; j += 8)
    tile[ty + j][tx] = W[(size_t)(by + ty + j) * BDIM + bx + tx];
  __syncthreads();
#pragma unroll
  for (int j = 0; j < 32; j += 8)
    O[(size_t)(bx + ty + j) * BDIM + by + tx] = __float2bfloat16(tile[tx][ty + j]);
}

// ------- wave-per-row LayerNorm (f32 in), +pos, optional extra outs -------
__global__ __launch_bounds__(256) void ln_kernel(
    const float* __restrict__ x, const float* __restrict__ g,
    const float* __restrict__ beta, const float* __restrict__ pos, int nmod,
    bf16* __restrict__ out1, bf16* __restrict__ out2, bf16* __restrict__ raw) {
  int w = threadIdx.x >> 6, lane = threadIdx.x & 63;
  int row = blockIdx.x * 4 + w;
  int c0 = lane * 8;
  const float* xr = x + (size_t)row * BDIM + c0;
  float4 v0 = *(const float4*)xr;
  float4 v1 = *(const float4*)(xr + 4);
  float f[8] = {v0.x, v0.y, v0.z, v0.w, v1.x, v1.y, v1.z, v1.w};
  float s = 0.f, sq = 0.f;
#pragma unroll
  for (int i = 0; i < 8; i++) {
    s += f[i];
    sq += f[i] * f[i];
  }
#pragma unroll
  for (int o = 1; o <= 32; o <<= 1) {
    s += __shfl_xor(s, o);
    sq += __shfl_xor(sq, o);
  }
  float mean = s * (1.f / BDIM);
  float var = sq * (1.f / BDIM) - mean * mean;
  float rstd = rsqrtf(var + 1e-5f);
  float4 g0 = *(const float4*)(g + c0);
  float4 g1 = *(const float4*)(g + c0 + 4);
  float4 b0 = *(const float4*)(beta + c0);
  float4 b1 = *(const float4*)(beta + c0 + 4);
  float gg[8] = {g0.x, g0.y, g0.z, g0.w, g1.x, g1.y, g1.z, g1.w};
  float bb[8] = {b0.x, b0.y, b0.z, b0.w, b1.x, b1.y, b1.z, b1.w};
  float pv[8] = {};
  if (pos) {
    int n = row % nmod;
    const float* pr = pos + (size_t)n * BDIM + c0;
    float4 p0 = *(const float4*)pr;
    float4 p1 = *(const float4*)(pr + 4);
    pv[0] = p0.x; pv[1] = p0.y; pv[2] = p0.z; pv[3] = p0.w;
    pv[4] = p1.x; pv[5] = p1.y; pv[6] = p1.z; pv[7] = p1.w;
  }
  short8v o1, o2, rw;
#pragma unroll
  for (int i = 0; i < 8; i++) {
    float nv = (f[i] - mean) * rstd * gg[i] + bb[i];
    o1[i] = f2bf(nv + pv[i]);
    o2[i] = f2bf(nv);
    rw[i] = f2bf(f[i]);
  }
  size_t ob = (size_t)row * BDIM + c0;
  *(short8v*)(out1 + ob) = o1;
  if (out2) *(short8v*)(out2 + ob) = o2;
  if (raw) *(short8v*)(raw + ob) = rw;
}

// ---------- wave-per-row LayerNorm (bf16 in, bf16 out) --------------------
__global__ __launch_bounds__(256) void lnb_kernel(
    const bf16* __restrict__ x, const float* __restrict__ g,
    const float* __restrict__ beta, bf16* __restrict__ out) {
  int w = threadIdx.x >> 6, lane = threadIdx.x & 63;
  int row = blockIdx.x * 4 + w;
  int c0 = lane * 8;
  short8v v = *(const short8v*)(x + (size_t)row * BDIM + c0);
  float f[8];
  float s = 0.f, sq = 0.f;
#pragma unroll
  for (int i = 0; i < 8; i++) {
    f[i] = bf2f(v[i]);
    s += f[i];
    sq += f[i] * f[i];
  }
#pragma unroll
  for (int o = 1; o <= 32; o <<= 1) {
    s += __shfl_xor(s, o);
    sq += __shfl_xor(sq, o);
  }
  float mean = s * (1.f / BDIM);
  float var = sq * (1.f / BDIM) - mean * mean;
  float rstd = rsqrtf(var + 1e-5f);
  float4 g0 = *(const float4*)(g + c0);
  float4 g1 = *(const float4*)(g + c0 + 4);
  float4 b0 = *(const float4*)(beta + c0);
  float4 b1 = *(const float4*)(beta + c0 + 4);
  float gg[8] = {g0.x, g0.y, g0.z, g0.w, g1.x, g1.y, g1.z, g1.w};
  float bb[8] = {b0.x, b0.y, b0.z, b0.w, b1.x, b1.y, b1.z, b1.w};
  short8v o1;
#pragma unroll
  for (int i = 0; i < 8; i++) o1[i] = f2bf((f[i] - mean) * rstd * gg[i] + bb[i]);
  *(short8v*)(out + (size_t)row * BDIM + c0) = o1;
}

// ---------------- pipelined MFMA GEMM body (R17-champion, verified) -------
// 128x128 tile, 8 waves (2x4), BK=64, 2 LDS buffers (64KB -> 2 blocks/CU),
// counted-vmcnt depth-2 prefetch, 2 raw barriers per K-step.
// EPI 0: bf16 = acc+bias; 1: bf16 = gelu_tanh; 3: bf16 = src+acc+bias;
// 4: f32 = src(bf16)+acc+bias
template <int EPI, int K, int LDX, int LDW, int N, int GX>
__device__ __forceinline__ void gemm_body(
    const bf16* __restrict__ X, const bf16* __restrict__ Wt,
    const float* __restrict__ bias, const void* __restrict__ src, void* outp,
    bf16* lds, int bid, int nwg) {
  int cpx = nwg >> 3;
  int nb = (bid & 7) * cpx + (bid >> 3);
  int bx = nb % GX, by = nb / GX;
  int row0 = by * 128, col0 = bx * 128;

  int t = threadIdx.x, w = t >> 6, lane = t & 63;
  int wr = w >> 2, wc = w & 3;
  int r16 = lane & 15, kg = lane >> 4;
  int srow = lane >> 3;
  int scol = ((lane & 7) ^ srow) * 8;

  const bf16* gA0 = X + (size_t)(row0 + w * 16 + srow) * LDX + scol;
  const bf16* gB0 = Wt + (size_t)(col0 + w * 16 + srow) * LDW + scol;

  f32x4 acc[4][2] = {};

  auto stage = [&](int kt, int buf) {
    bf16* base = lds + buf * 16384;
    int ke = kt << 6;
#pragma unroll
    for (int j = 0; j < 2; j++) {
      GLOAD_LDS16(gA0 + ke + (size_t)j * 8 * LDX, base + (w * 16 + j * 8) * 64);
      GLOAD_LDS16(gB0 + ke + (size_t)j * 8 * LDW,
                  base + 8192 + (w * 16 + j * 8) * 64);
    }
  };

  auto compute = [&](int buf) {
    const char* base = (const char*)(lds + buf * 16384);
#pragma unroll
    for (int ksub = 0; ksub < 2; ksub++) {
      int cc = (ksub * 64 + kg * 16) ^ ((r16 & 7) << 4);
      short8v a[4], b[2];
#pragma unroll
      for (int m = 0; m < 4; m++)
        a[m] = *(const short8v*)(base + (wr * 64 + m * 16 + r16) * 128 + cc);
#pragma unroll
      for (int n = 0; n < 2; n++)
        b[n] = *(const short8v*)(base + 16384 + (wc * 32 + n * 16 + r16) * 128 + cc);
#pragma unroll
      for (int m = 0; m < 4; m++)
#pragma unroll
        for (int n = 0; n < 2; n++)
          acc[m][n] =
              __builtin_amdgcn_mfma_f32_16x16x32_bf16(a[m], b[n], acc[m][n], 0, 0, 0);
    }
  };

  constexpr int NT = K >> 6;
  stage(0, 0);
  stage(1, 1);
#pragma unroll
  for (int tt = 0; tt < NT; tt++) {
    if (tt < NT - 1)
      asm volatile("s_waitcnt vmcnt(4)" ::: "memory");
    else
      asm volatile("s_waitcnt vmcnt(0)" ::: "memory");
    __builtin_amdgcn_s_barrier();
    asm volatile("" ::: "memory");
    compute(tt & 1);
    asm volatile("" ::: "memory");
    __builtin_amdgcn_s_barrier();
    asm volatile("" ::: "memory");
    if (tt + 2 < NT) stage(tt + 2, tt & 1);
  }

#pragma unroll
  for (int n = 0; n < 2; n++) {
    int col = col0 + wc * 32 + n * 16 + r16;
    float bv = bias ? bias[col] : 0.f;
#pragma unroll
    for (int m = 0; m < 4; m++)
#pragma unroll
      for (int r = 0; r < 4; r++) {
        int row = row0 + wr * 64 + m * 16 + kg * 4 + r;
        size_t o = (size_t)row * N + col;
        float val = acc[m][n][r] + bv;
        if (EPI == 0) {
          ((bf16*)outp)[o] = __float2bfloat16(val);
        } else if (EPI == 1) {
          // gelu_tanh(x) = x * sigmoid(1.5957691*(x + 0.044715 x^3))
          float z = 1.5957691f * val * (1.f + 0.044715f * val * val);
          float gl = val / (1.f + __expf(-z));
          ((bf16*)outp)[o] = __float2bfloat16(gl);
        } else if (EPI == 3) {
          ((bf16*)outp)[o] = __float2bfloat16(bf2f(((const short*)src)[o]) + val);
        } else {
          ((float*)outp)[o] = bf2f(((const short*)src)[o]) + val;
        }
      }
  }
}

template <int EPI, int K, int LDX, int LDW, int N, int GX>
__global__ __launch_bounds__(512) void gemm_kernel(
    const bf16* __restrict__ X, const bf16* __restrict__ Wt,
    const float* __restrict__ bias, const void* __restrict__ src, void* outp) {
  extern __shared__ bf16 lds[];
  gemm_body<EPI, K, LDX, LDW, N, GX>(X, Wt, bias, src, outp, lds, blockIdx.x,
                                     gridDim.x);
}

// fused k+v projections: blocks [0,HALF) -> (X0,W0,b0,o0); rest -> second set
template <int K, int LDX, int LDW, int N, int GX, int HALF>
__global__ __launch_bounds__(512) void gemm_kv_kernel(
    const bf16* __restrict__ X0, const bf16* __restrict__ W0,
    const float* __restrict__ b0, void* o0, const bf16* __restrict__ X1,
    const bf16* __restrict__ W1, const float* __restrict__ b1, void* o1) {
  extern __shared__ bf16 lds[];
  int bid = blockIdx.x;
  if (bid < HALF)
    gemm_body<0, K, LDX, LDW, N, GX>(X0, W0, b0, nullptr, o0, lds, bid, HALF);
  else
    gemm_body<0, K, LDX, LDW, N, GX>(X1, W1, b1, nullptr, o1, lds, bid - HALF,
                                     HALF);
}

// ---- ctx: fused k-softmax (over positions) + ctxT[bh][vc][kc] einsum -----
__global__ __launch_bounds__(256) void ctx_kernel(
    const bf16* __restrict__ kproj, const bf16* __restrict__ vbuf,
    bf16* __restrict__ ctxT) {
  int bh = blockIdx.x;
  int b = bh >> 3, h = bh & 7;
  __shared__ bf16 lk[NN4][DK], lv[NN4][DK];
  int t = threadIdx.x;
#pragma unroll
  for (int i = 0; i < 16; i++) {
    int idx = i * 256 + t;
    int n = idx >> 6, c = idx & 63;
    size_t gaddr = (size_t)b * NN4 * BDIM + (size_t)n * BDIM + h * DK + c;
    lk[n][c] = kproj[gaddr];
    lv[n][c] = vbuf[gaddr];
  }
  __syncthreads();
  if (t < 64) {
    int c = t;
    float e[NN4];
    float m = -1e30f;
#pragma unroll
    for (int n = 0; n < NN4; n++) {
      e[n] = bf2f(*(short*)&lk[n][c]);
      m = fmaxf(m, e[n]);
    }
    float s = 0.f;
#pragma unroll
    for (int n = 0; n < NN4; n++) {
      e[n] = __expf(e[n] - m);
      s += e[n];
    }
    float inv = 1.f / s;
#pragma unroll
    for (int n = 0; n < NN4; n++) lk[n][c] = __float2bfloat16(e[n] * inv);
  }
  __syncthreads();
  int vc = t >> 2;
  int kc0 = (t & 3) * 16;
  float acc[16] = {};
  for (int n = 0; n < NN4; n++) {
    float vv = __bfloat162float(lv[n][vc]);
#pragma unroll
    for (int i = 0; i < 16; i++)
      acc[i] += vv * __bfloat162float(lk[n][kc0 + i]);
  }
  size_t o = (size_t)bh * 4096 + (size_t)vc * 64 + kc0;
#pragma unroll
  for (int i = 0; i < 16; i++) ctxT[o + i] = __float2bfloat16(acc[i]);
}

// ---- att: fused q-softmax (in-register, over 64 head channels) + GEMM ----
__global__ __launch_bounds__(256) void att_kernel(
    const bf16* __restrict__ qproj, const bf16* __restrict__ ctxT,
    bf16* __restrict__ att) {
  int bh = blockIdx.x;
  int b = bh >> 3, h = bh & 7;
  int t = threadIdx.x, w = t >> 6, lane = t & 63;
  int r16 = lane & 15, kg = lane >> 4;
  f32x4 acc[4][4] = {};
  const bf16* qb = qproj + (size_t)b * NN3 * BDIM + h * DK;
  const bf16* cb = ctxT + (size_t)bh * 4096;
  short8v bb[2][4];
#pragma unroll
  for (int kt = 0; kt < 2; kt++)
#pragma unroll
    for (int ni = 0; ni < 4; ni++)
      bb[kt][ni] = *(const short8v*)(cb + (ni * 16 + r16) * 64 + kt * 32 + kg * 8);
#pragma unroll
  for (int mi = 0; mi < 4; mi++) {
    int rrow = w * 64 + mi * 16 + r16;
    short8v a0 = *(const short8v*)(qb + (size_t)rrow * BDIM + kg * 8);
    short8v a1 = *(const short8v*)(qb + (size_t)rrow * BDIM + 32 + kg * 8);
    float f[16];
#pragma unroll
    for (int i = 0; i < 8; i++) {
      f[i] = bf2f(a0[i]);
      f[8 + i] = bf2f(a1[i]);
    }
    float m = f[0];
#pragma unroll
    for (int i = 1; i < 16; i++) m = fmaxf(m, f[i]);
    m = fmaxf(m, __shfl_xor(m, 16));
    m = fmaxf(m, __shfl_xor(m, 32));
    float s = 0.f;
#pragma unroll
    for (int i = 0; i < 16; i++) {
      f[i] = __expf(f[i] - m);
      s += f[i];
    }
    s += __shfl_xor(s, 16);
    s += __shfl_xor(s, 32);
    float inv = 1.f / s;
    short8v A0, A1;
#pragma unroll
    for (int i = 0; i < 8; i++) {
      A0[i] = f2bf(f[i] * inv);
      A1[i] = f2bf(f[8 + i] * inv);
    }
#pragma unroll
    for (int ni = 0; ni < 4; ni++) {
      acc[mi][ni] = __builtin_amdgcn_mfma_f32_16x16x32_bf16(A0, bb[0][ni], acc[mi][ni], 0, 0, 0);
      acc[mi][ni] = __builtin_amdgcn_mfma_f32_16x16x32_bf16(A1, bb[1][ni], acc[mi][ni], 0, 0, 0);
    }
  }
#pragma unroll
  for (int mi = 0; mi < 4; mi++)
#pragma unroll
    for (int ni = 0; ni < 4; ni++)
#pragma unroll
      for (int r = 0; r < 4; r++) {
        int row = w * 64 + mi * 16 + kg * 4 + r;
        int col = ni * 16 + r16;
        att[(size_t)(b * NN3 + row) * BDIM + h * DK + col] =
            __float2bfloat16(acc[mi][ni][r]);
      }
}

extern "C" void kernel_launch(void* const* d_in, const int* in_sizes, int n_in,
                              void* d_out, int out_size, void* d_ws, size_t ws_size,
                              hipStream_t stream) {
  const float* f3 = (const float*)d_in[0];
  const float* f4 = (const float*)d_in[1];
  const float* pos3 = (const float*)d_in[2];
  const float* pos4 = (const float*)d_in[3];
  const float* ln1_g = (const float*)d_in[4];
  const float* ln1_b = (const float*)d_in[5];
  const float* ln2_g = (const float*)d_in[6];
  const float* ln2_b = (const float*)d_in[7];
  const float* ln3_g = (const float*)d_in[8];
  const float* ln3_b = (const float*)d_in[9];
  const float* Wq = (const float*)d_in[10];
  const float* bq = (const float*)d_in[11];
  const float* Wk = (const float*)d_in[12];
  const float* bk = (const float*)d_in[13];
  const float* Wv = (const float*)d_in[14];
  const float* bv = (const float*)d_in[15];
  const float* Wr = (const float*)d_in[16];
  const float* br = (const float*)d_in[17];
  const float* W1 = (const float*)d_in[18];
  const float* b1 = (const float*)d_in[19];
  const float* W2 = (const float*)d_in[20];
  const float* b2 = (const float*)d_in[21];
  float* out = (float*)d_out;

  const int M3 = NBATCH * NN3;  // 65536
  const int M4 = NBATCH * NN4;  // 16384
  const int MC = M3 / 2;        // 32768 MLP row-chunk

  char* ws = (char*)d_ws;
  size_t off = 0;
  auto alloc = [&](size_t bytes) {
    size_t r = off;
    off = (off + bytes + 255) & ~(size_t)255;
    return r;
  };
  size_t oWqt = alloc((size_t)BDIM * BDIM * 2);
  size_t oWkt = alloc((size_t)BDIM * BDIM * 2);
  size_t oWvt = alloc((size_t)BDIM * BDIM * 2);
  size_t oWrt = alloc((size_t)BDIM * BDIM * 2);
  size_t oW1t = alloc((size_t)BDIM * NMLP * 2);
  size_t oW2t = alloc((size_t)BDIM * NMLP * 2);
  size_t oXQ = alloc((size_t)M3 * BDIM * 2);  // ln(f3)+pos3 -> att -> Yn
  size_t oXK = alloc((size_t)M4 * BDIM * 2);
  size_t oXV = alloc((size_t)M4 * BDIM * 2);
  size_t oQF = alloc((size_t)M3 * BDIM * 2);  // q proj -> F3O
  size_t oKF = alloc((size_t)M4 * BDIM * 2);
  size_t oVF = alloc((size_t)M4 * BDIM * 2);
  size_t oF3B = alloc((size_t)M3 * BDIM * 2);  // bf16 copy of f3
  size_t oCT = alloc((size_t)NBATCH * NHEADS * DK * DK * 2);
  size_t oH1 = alloc((size_t)MC * NMLP * 2);  // 128MB hidden row-chunk
  (void)ws_size;

  bf16* Wqt = (bf16*)(ws + oWqt);
  bf16* Wkt = (bf16*)(ws + oWkt);
  bf16* Wvt = (bf16*)(ws + oWvt);
  bf16* Wrt = (bf16*)(ws + oWrt);
  bf16* W1t = (bf16*)(ws + oW1t);
  bf16* W2t = (bf16*)(ws + oW2t);
  bf16* XQ = (bf16*)(ws + oXQ);
  bf16* XK = (bf16*)(ws + oXK);
  bf16* XV = (bf16*)(ws + oXV);
  bf16* QF = (bf16*)(ws + oQF);
  bf16* KF = (bf16*)(ws + oKF);
  bf16* VF = (bf16*)(ws + oVF);
  bf16* F3B = (bf16*)(ws + oF3B);
  bf16* CT = (bf16*)(ws + oCT);
  bf16* H1 = (bf16*)(ws + oH1);
  bf16* ATT = XQ;   // reuse (XQ dead after q projection)
  bf16* F3O = QF;   // reuse (QF dead after att)
  bf16* YN = XQ;    // reuse (ATT dead after outproj)

  // dynamic-LDS caps
  hipFuncSetAttribute((const void*)gemm_kernel<0, 512, 512, 512, 512, 4>,
                      hipFuncAttributeMaxDynamicSharedMemorySize, 65536);
  hipFuncSetAttribute((const void*)gemm_kernel<1, 512, 512, 512, 2048, 16>,
                      hipFuncAttributeMaxDynamicSharedMemorySize, 65536);
  hipFuncSetAttribute((const void*)gemm_kernel<3, 512, 512, 512, 512, 4>,
                      hipFuncAttributeMaxDynamicSharedMemorySize, 65536);
  hipFuncSetAttribute((const void*)gemm_kernel<4, 2048, 2048, 2048, 512, 4>,
                      hipFuncAttributeMaxDynamicSharedMemorySize, 65536);
  hipFuncSetAttribute((const void*)gemm_kv_kernel<512, 512, 512, 512, 4, 512>,
                      hipFuncAttributeMaxDynamicSharedMemorySize, 65536);

  // ---- weight conversion (batched + W1/W2) ----
  convt4_kernel<<<dim3(16, 16, 4), dim3(32, 8), 0, stream>>>(
      Wq, Wk, Wv, Wr, Wqt, Wkt, Wvt, Wrt);
  convt_kernel<<<dim3(NMLP / 32, BDIM / 32), dim3(32, 8), 0, stream>>>(W1, W1t, BDIM, NMLP);
  convt_kernel<<<dim3(BDIM / 32, NMLP / 32), dim3(32, 8), 0, stream>>>(W2, W2t, NMLP, BDIM);

  // ---- layernorms (f3 pass also emits bf16 raw copy for residual) ----
  ln_kernel<<<M3 / 4, 256, 0, stream>>>(f3, ln1_g, ln1_b, pos3, NN3, XQ, nullptr, F3B);
  ln_kernel<<<M4 / 4, 256, 0, stream>>>(f4, ln2_g, ln2_b, pos4, NN4, XK, XV, nullptr);

  // ---- projections (q; k+v fused into one launch) ----
  gemm_kernel<0, 512, 512, 512, 512, 4><<<(BDIM / 128) * (M3 / 128), 512, 65536, stream>>>(
      XQ, Wqt, bq, nullptr, QF);
  gemm_kv_kernel<512, 512, 512, 512, 4, 512><<<1024, 512, 65536, stream>>>(
      XK, Wkt, bk, KF, XV, Wvt, bv, VF);

  // ---- context (fused k-softmax) + att (fused q-softmax) ----
  ctx_kernel<<<NBATCH * NHEADS, 256, 0, stream>>>(KF, VF, CT);
  att_kernel<<<NBATCH * NHEADS, 256, 0, stream>>>(QF, CT, ATT);

  // ---- output projection: F3O(bf16) = f3(bf16 copy) + att @ Wr + br ----
  gemm_kernel<3, 512, 512, 512, 512, 4><<<(BDIM / 128) * (M3 / 128), 512, 65536, stream>>>(
      ATT, Wrt, br, F3B, F3O);

  // ---- LN3: YN(bf16) = ln(F3O) ----
  lnb_kernel<<<M3 / 4, 256, 0, stream>>>(F3O, ln3_g, ln3_b, YN);

  // ---- MLP, 2 row-chunks of 32768 ----
  for (int c = 0; c < 2; c++) {
    const bf16* Yc = YN + (size_t)c * MC * BDIM;
    const bf16* Fc = F3O + (size_t)c * MC * BDIM;
    float* outc = out + (size_t)c * MC * BDIM;
    gemm_kernel<1, 512, 512, 512, 2048, 16><<<(NMLP / 128) * (MC / 128), 512, 65536, stream>>>(
        Yc, W1t, b1, nullptr, H1);
    gemm_kernel<4, 2048, 2048, 2048, 512, 4><<<(BDIM / 128) * (MC / 128), 512, 65536, stream>>>(
        H1, W2t, b2, Fc, outc);
  }
}